// Round 3
// baseline (263.982 us; speedup 1.0000x reference)
//
#include <hip/hip_runtime.h>
#include <math.h>

#if __has_builtin(__builtin_amdgcn_exp2f)
#define EXP2F(x) __builtin_amdgcn_exp2f(x)
#else
#define EXP2F(x) exp2f(x)
#endif
#if __has_builtin(__builtin_amdgcn_sqrtf)
#define SQRTF(x) __builtin_amdgcn_sqrtf(x)
#else
#define SQRTF(x) sqrtf(x)
#endif

#define NPTS 8192
#define JT 64               // j per job (LDS staged)
#define ITILE 512           // i per job (2 per thread, 256 threads)
#define T16 16              // 512-tiles per dimension
#define NTRI 136            // upper-tri 512x512 tile count
#define NJOB_AB 2048        // 16 i-tiles * 128 j-chunks
#define NJOB_TRI 1088       // 136 * 8 j-chunks
#define NJOBS (NJOB_AB + 2 * NJOB_TRI)  // 4224
#define NBLK_PAIR 1024
#define L2E 1.4426950408889634f

// acc layout: [0..2] AA bands, [3..5] BB, [6..8] AB, [9] sum d, [10] sum d^2

__device__ inline double wred_d(double v) {
#pragma unroll
  for (int o = 32; o > 0; o >>= 1) v += __shfl_down(v, o, 64);
  return v;
}

__device__ inline double bred(double v, double* sm) {
  v = wred_d(v);
  __syncthreads();
  if ((threadIdx.x & 63) == 0) sm[threadIdx.x >> 6] = v;
  __syncthreads();
  return sm[0] + sm[1] + sm[2] + sm[3];
}

// wave 0: reduce 64 prep slots -> smean[8] = {Sb,Qb,Mxb,Myb,St,Qt,Mxt,Myt}
__device__ inline void slot_reduce(const double* slot, double* smean) {
  if (threadIdx.x < 64) {
    int l = threadIdx.x;
    const double* sl = slot + l * 4;
#pragma unroll
    for (int c = 0; c < 4; ++c) {
      double v = sl[c];
      double vb = (l < 32) ? v : 0.0;
      double vt = (l < 32) ? 0.0 : v;
      vb = wred_d(vb);
      vt = wred_d(vt);
      if (l == 0) {
        smean[c] = vb;
        smean[4 + c] = vt;
      }
    }
  }
}

__global__ __launch_bounds__(256) void prep_kernel(
    const float* __restrict__ base, const float* __restrict__ target,
    const float* __restrict__ log_sigmas, const float* __restrict__ log_scale,
    const float* __restrict__ w1, const float* __restrict__ b1,
    const float* __restrict__ w2, const float* __restrict__ b2,
    float2* __restrict__ pxy, float* __restrict__ pu,
    double* __restrict__ slot, double* __restrict__ acc,
    unsigned* __restrict__ jctr, unsigned* __restrict__ fctr, int n) {
  __shared__ double sm[4];
  int gid = blockIdx.x * 256 + threadIdx.x;
  int isT = gid >= n;  // uniform per block (n % 256 == 0)
  const float* pts = isT ? target : base;
  int idx = isT ? gid - n : gid;
  float ex = __expf(log_scale[0]);
  float ey = __expf(log_scale[1]);
  float s2 = __expf(log_sigmas[2]);
  float r2 = __fsqrt_rn(L2E / (2.f * s2 * s2));  // coord pre-scale for band 2
  float2 p = ((const float2*)pts)[idx];
  float xr = p.x * ex, yr = p.y * ey;  // MLP input space (no r2!)
  float logit = b2[0];
#pragma unroll
  for (int k = 0; k < 32; ++k) {
    float h = fmaf(xr, w1[k], fmaf(yr, w1[32 + k], b1[k]));
    h = fmaxf(h, 0.f);
    logit = fmaf(h, w2[k], logit);
  }
  float u = fmaxf(logit, 0.f) + log1pf(__expf(-fabsf(logit))) + 1e-6f;
  float X = xr * r2, Y = yr * r2;
  pxy[gid] = make_float2(X, Y);
  pu[gid] = u;
  double su = bred((double)u, sm);
  double qu = bred((double)u * (double)u, sm);
  double mx = bred((double)u * (double)X, sm);
  double my = bred((double)u * (double)Y, sm);
  if (threadIdx.x == 0) {
    double* s = slot + blockIdx.x * 4;
    s[0] = su;
    s[1] = qu;
    s[2] = mx;
    s[3] = my;
    if (blockIdx.x == 0) {
      for (int i = 0; i < 11; ++i) acc[i] = 0.0;
      *jctr = 0u;
      *fctr = 0u;
    }
  }
}

template <bool AB, bool FAST>
__device__ inline void tile_loop(const float4* sxy4, const float2* su2,
                                 const float2* sb2, float x0, float y0,
                                 float x1, float y1, float al0, float al1,
                                 float rr0, float rr1, float acc[2][3],
                                 float& sdo, float& sqo) {
  float sd = 0.f, sq = 0.f;
#pragma unroll 2
  for (int jj = 0; jj < JT / 2; ++jj) {
    float4 xy = sxy4[jj];  // {x0,y0,x1,y1} for two j points (broadcast)
    float2 u2 = su2[jj];
    float bj[2];
    if constexpr (AB) {
      float2 b2v = sb2[jj];
      bj[0] = b2v.x;
      bj[1] = b2v.y;
    }
    float xj[2] = {xy.x, xy.z};
    float yj[2] = {xy.y, xy.w};
    float uj[2] = {u2.x, u2.y};
#pragma unroll
    for (int q = 0; q < 2; ++q) {
#pragma unroll
      for (int i = 0; i < 2; ++i) {
        float dx = (i ? x1 : x0) - xj[q];
        float dy = (i ? y1 : y0) - yj[q];
        float s = fmaf(dy, dy, dx * dx);  // = d2_centered * (ln2e/2s2^2)
        float k2 = EXP2F(-s);
        float k0, k1;
        if constexpr (FAST) {
          float t = k2 * k2;
          k1 = t * t;  // k2^4  (sigma ratio 1:2)
          float t1 = k1 * k1;
          k0 = t1 * t1;  // k2^16 (sigma ratio 1:4)
        } else {
          k1 = EXP2F(-s * rr1);
          k0 = EXP2F(-s * rr0);
        }
        acc[i][0] = fmaf(uj[q], k0, acc[i][0]);
        acc[i][1] = fmaf(uj[q], k1, acc[i][1]);
        acc[i][2] = fmaf(uj[q], k2, acc[i][2]);
        if constexpr (AB) {
          float d2u = fmaxf((s + (i ? al1 : al0)) - bj[q], 0.f);
          sd += SQRTF(d2u);
          sq += d2u;
        }
      }
    }
  }
  sdo = sd;
  sqo = sq;
}

__global__ __launch_bounds__(256, 4) void pair_kernel(
    const float2* __restrict__ pxy, const float* __restrict__ pu,
    const double* __restrict__ slot, double* __restrict__ acc,
    unsigned* __restrict__ jctr, unsigned* __restrict__ fctr,
    const float* __restrict__ log_sigmas, const float* __restrict__ g_w1,
    const float* __restrict__ g_b1, const float* __restrict__ g_w2,
    const float* __restrict__ g_b2, const float* __restrict__ bias,
    float* __restrict__ out, int n) {
  __shared__ __align__(16) float2 sxy[JT];
  __shared__ __align__(16) float su[JT];
  __shared__ __align__(16) float sb[JT];
  __shared__ double sm[4];
  __shared__ double smean[8];
  __shared__ int sjid;
  __shared__ int lastf;

  slot_reduce(slot, smean);
  __syncthreads();
  float cx = (float)(smean[2] / smean[0] - smean[6] / smean[4]);
  float cy = (float)(smean[3] / smean[0] - smean[7] / smean[4]);
  float cx2 = 2.f * cx, cy2 = 2.f * cy;
  float cc = cx * cx + cy * cy;

  float s0 = __expf(log_sigmas[0]);
  float s1 = __expf(log_sigmas[1]);
  float s2 = __expf(log_sigmas[2]);
  float rr0 = (s2 * s2) / (s0 * s0);
  float rr1 = (s2 * s2) / (s1 * s1);
  bool fast = (fabsf(rr0 - 16.f) <= 0.016f) && (fabsf(rr1 - 4.f) <= 0.004f);

  for (;;) {
    __syncthreads();  // protect sjid + LDS reuse across jobs
    if (threadIdx.x == 0) sjid = (int)atomicAdd(jctr, 1u);
    __syncthreads();
    int job = sjid;
    if (job >= NJOBS) break;

    int m, it, jt = 0, j0;
    if (job < NJOB_AB) {  // AB first (heavier) so light jobs drain last
      m = 2;
      it = job >> 7;
      j0 = (job & 127) * JT;
    } else {
      int r = job - NJOB_AB;
      m = (r < NJOB_TRI) ? 0 : 1;
      if (m == 1) r -= NJOB_TRI;
      int tri = r >> 3;
      int q = r & 7;
      int idx = tri, len = T16;
      it = 0;
      while (idx >= len) {
        idx -= len;
        --len;
        ++it;
      }
      jt = it + idx;
      j0 = jt * ITILE + q * JT;
    }
    const float2* pxyI = pxy + ((m == 1) ? n : 0);
    const float* puI = pu + ((m == 1) ? n : 0);
    const float2* pxyJ = pxy + ((m == 0) ? 0 : n);
    const float* puJ = pu + ((m == 0) ? 0 : n);

    if (threadIdx.x < JT) {
      float2 v = pxyJ[j0 + threadIdx.x];
      sxy[threadIdx.x] = v;
      su[threadIdx.x] = puJ[j0 + threadIdx.x];
      if (m == 2) sb[threadIdx.x] = fmaf(cx2, v.x, cy2 * v.y);  // beta_j
    }
    __syncthreads();

    int i0 = it * ITILE + threadIdx.x;
    float2 P0 = pxyI[i0], P1 = pxyI[i0 + 256];
    float u0 = puI[i0], u1 = puI[i0 + 256];
    float x0 = P0.x, y0 = P0.y, x1 = P1.x, y1 = P1.y;
    float al0 = 0.f, al1 = 0.f;
    if (m == 2) {  // center i-side; alpha for uncentered-distance recovery
      x0 -= cx; y0 -= cy; x1 -= cx; y1 -= cy;
      al0 = fmaf(cx2, x0, cy2 * y0) + cc;
      al1 = fmaf(cx2, x1, cy2 * y1) + cc;
    }

    float accf[2][3] = {};
    float sd = 0.f, sq = 0.f;
    const float4* sxy4 = reinterpret_cast<const float4*>(sxy);
    const float2* su2 = reinterpret_cast<const float2*>(su);
    const float2* sb2 = reinterpret_cast<const float2*>(sb);
    if (m == 2) {
      if (fast)
        tile_loop<true, true>(sxy4, su2, sb2, x0, y0, x1, y1, al0, al1, rr0,
                              rr1, accf, sd, sq);
      else
        tile_loop<true, false>(sxy4, su2, sb2, x0, y0, x1, y1, al0, al1, rr0,
                               rr1, accf, sd, sq);
    } else {
      if (fast)
        tile_loop<false, true>(sxy4, su2, sb2, x0, y0, x1, y1, al0, al1, rr0,
                               rr1, accf, sd, sq);
      else
        tile_loop<false, false>(sxy4, su2, sb2, x0, y0, x1, y1, al0, al1, rr0,
                                rr1, accf, sd, sq);
    }

    double wgt = (m != 2 && jt != it) ? 2.0 : 1.0;  // symmetric off-diag
    double c0 = (double)u0 * accf[0][0] + (double)u1 * accf[1][0];
    double c1 = (double)u0 * accf[0][1] + (double)u1 * accf[1][1];
    double c2 = (double)u0 * accf[0][2] + (double)u1 * accf[1][2];
    double r0 = bred(c0, sm) * wgt;
    double r1 = bred(c1, sm) * wgt;
    double r2d = bred(c2, sm) * wgt;
    if (threadIdx.x == 0) {
      atomicAdd(&acc[3 * m + 0], r0);
      atomicAdd(&acc[3 * m + 1], r1);
      atomicAdd(&acc[3 * m + 2], r2d);
    }
    if (m == 2) {
      double rsd = bred((double)sd, sm);
      double rsq = bred((double)sq, sm);
      if (threadIdx.x == 0) {
        atomicAdd(&acc[9], rsd);
        atomicAdd(&acc[10], rsq);
      }
    }
  }

  // ---- last-block final (ticket + device fence) ----
  if (threadIdx.x == 0) {
    __threadfence();
    unsigned old = atomicAdd(fctr, 1u);
    lastf = (old == NBLK_PAIR - 1) ? 1 : 0;
  }
  __syncthreads();
  if (!lastf) return;
  __threadfence();

  if (threadIdx.x == 0) {
    double v[11];
    for (int i = 0; i < 11; ++i) v[i] = atomicAdd(&acc[i], 0.0);  // coherent read
    double Sb = smean[0], Qb = smean[1], St = smean[4], Qt = smean[5];
    double pband[3];
    for (int s = 0; s < 3; ++s)
      pband[s] = v[s] / (Sb * Sb) + v[3 + s] / (St * St) -
                 2.0 * v[6 + s] / (Sb * St);
    double s2d = (double)s2;
    double r2sq = (double)L2E / (2.0 * s2d * s2d);
    double sd_real = v[9] / sqrt(r2sq);
    double sq_real = v[10] / r2sq;
    double NN = (double)n;
    double NM = NN * NN;
    double mean_d = sd_real / NM;
    double var_d = (sq_real - sd_real * sd_real / NM) / (NM - 1.0);
    double wv = (Qb / (Sb * Sb) - 1.0 / NN) / (NN - 1.0) +
                (Qt / (St * St) - 1.0 / NN) / (NN - 1.0);
    float st[4] = {(float)mean_d, (float)var_d, 0.f, (float)wv};
    float gl[3] = {g_b2[0], g_b2[1], g_b2[2]};
    for (int k = 0; k < 32; ++k) {
      float h = g_b1[k];
      for (int c = 0; c < 4; ++c) h = fmaf(st[c], g_w1[c * 32 + k], h);
      h = fmaxf(h, 0.f);
      for (int s = 0; s < 3; ++s) gl[s] = fmaf(h, g_w2[k * 3 + s], gl[s]);
    }
    float gw[3];
    float gsum = 0.f;
    for (int s = 0; s < 3; ++s) {
      gw[s] = fmaxf(gl[s], 0.f) + log1pf(__expf(-fabsf(gl[s])));
      gsum += gw[s];
    }
    double r = 0.0;
    for (int s = 0; s < 3; ++s) r += (double)(gw[s] / gsum) * pband[s];
    out[0] = (float)(r + (double)bias[0]);
  }
}

extern "C" void kernel_launch(void* const* d_in, const int* in_sizes, int n_in,
                              void* d_out, int out_size, void* d_ws,
                              size_t ws_size, hipStream_t stream) {
  const float* base = (const float*)d_in[0];
  const float* target = (const float*)d_in[1];
  const float* log_sigmas = (const float*)d_in[2];
  const float* log_scale = (const float*)d_in[3];
  const float* wn_w1 = (const float*)d_in[4];
  const float* wn_b1 = (const float*)d_in[5];
  const float* wn_w2 = (const float*)d_in[6];
  const float* wn_b2 = (const float*)d_in[7];
  const float* g_w1 = (const float*)d_in[8];
  const float* g_b1 = (const float*)d_in[9];
  const float* g_w2 = (const float*)d_in[10];
  const float* g_b2 = (const float*)d_in[11];
  const float* bias = (const float*)d_in[12];
  int n = in_sizes[0] / 2;  // 8192

  double* dbase = (double*)d_ws;
  double* slot = dbase;        // 64 * 4
  double* acc = dbase + 256;   // 11 (+1 pad)
  double* dend = acc + 12;
  float2* pxy = (float2*)dend;        // 2n
  float* pu = (float*)(pxy + 2 * n);  // 2n
  unsigned* jctr = (unsigned*)(pu + 2 * n);
  unsigned* fctr = jctr + 1;

  prep_kernel<<<(2 * n) / 256, 256, 0, stream>>>(
      base, target, log_sigmas, log_scale, wn_w1, wn_b1, wn_w2, wn_b2, pxy, pu,
      slot, acc, jctr, fctr, n);
  pair_kernel<<<NBLK_PAIR, 256, 0, stream>>>(pxy, pu, slot, acc, jctr, fctr,
                                             log_sigmas, g_w1, g_b1, g_w2,
                                             g_b2, bias, (float*)d_out, n);
}

// Round 4
// 158.586 us; speedup vs baseline: 1.6646x; 1.6646x over previous
//
#include <hip/hip_runtime.h>
#include <math.h>

#if __has_builtin(__builtin_amdgcn_exp2f)
#define EXP2F(x) __builtin_amdgcn_exp2f(x)
#else
#define EXP2F(x) exp2f(x)
#endif
#if __has_builtin(__builtin_amdgcn_sqrtf)
#define SQRTF(x) __builtin_amdgcn_sqrtf(x)
#else
#define SQRTF(x) sqrtf(x)
#endif

#define NPTS 8192
#define JT 64                // j per block (LDS staged)
#define ITILE 1024           // i per block (4 per thread, 256 threads)
#define T8 8                 // 1024-tiles per dimension
#define NTRI8 36             // upper-tri 1024x1024 tiles
#define JCH 16               // 64-j chunks per 1024-tile
#define NJOB_AB 1024         // 8 i-tiles * 128 j-chunks
#define NJOB_TRI 576         // 36 * 16
#define NBLK (NJOB_AB + 2 * NJOB_TRI)  // 2176
#define L2E 1.4426950408889634f

__device__ inline double wred_d(double v) {
#pragma unroll
  for (int o = 32; o > 0; o >>= 1) v += __shfl_down(v, o, 64);
  return v;
}

__device__ inline double bred(double v, double* sm) {
  v = wred_d(v);
  __syncthreads();
  if ((threadIdx.x & 63) == 0) sm[threadIdx.x >> 6] = v;
  __syncthreads();
  return sm[0] + sm[1] + sm[2] + sm[3];
}

// wave 0: reduce 64 prep slots -> smean[8] = {Sb,Qb,Mxb,Myb,St,Qt,Mxt,Myt}
__device__ inline void slot_reduce(const double* slot, double* smean) {
  if (threadIdx.x < 64) {
    int l = threadIdx.x;
    const double* sl = slot + l * 4;
#pragma unroll
    for (int c = 0; c < 4; ++c) {
      double v = sl[c];
      double vb = (l < 32) ? v : 0.0;
      double vt = (l < 32) ? 0.0 : v;
      vb = wred_d(vb);
      vt = wred_d(vt);
      if (l == 0) {
        smean[c] = vb;
        smean[4 + c] = vt;
      }
    }
  }
}

__global__ __launch_bounds__(256) void prep_kernel(
    const float* __restrict__ base, const float* __restrict__ target,
    const float* __restrict__ log_sigmas, const float* __restrict__ log_scale,
    const float* __restrict__ w1, const float* __restrict__ b1,
    const float* __restrict__ w2, const float* __restrict__ b2,
    float2* __restrict__ pxy, float* __restrict__ pu,
    double* __restrict__ slot, unsigned* __restrict__ fctr, int n) {
  __shared__ double sm[4];
  int gid = blockIdx.x * 256 + threadIdx.x;
  int isT = gid >= n;  // uniform per block (n % 256 == 0)
  const float* pts = isT ? target : base;
  int idx = isT ? gid - n : gid;
  float ex = __expf(log_scale[0]);
  float ey = __expf(log_scale[1]);
  float s2 = __expf(log_sigmas[2]);
  float r2 = __fsqrt_rn(L2E / (2.f * s2 * s2));  // coord pre-scale, band 2
  float2 p = ((const float2*)pts)[idx];
  float xr = p.x * ex, yr = p.y * ey;  // MLP input space (no r2!)
  float logit = b2[0];
#pragma unroll
  for (int k = 0; k < 32; ++k) {
    float h = fmaf(xr, w1[k], fmaf(yr, w1[32 + k], b1[k]));
    h = fmaxf(h, 0.f);
    logit = fmaf(h, w2[k], logit);
  }
  float u = fmaxf(logit, 0.f) + log1pf(__expf(-fabsf(logit))) + 1e-6f;
  float X = xr * r2, Y = yr * r2;
  pxy[gid] = make_float2(X, Y);
  pu[gid] = u;
  double su = bred((double)u, sm);
  double qu = bred((double)u * (double)u, sm);
  double mx = bred((double)u * (double)X, sm);
  double my = bred((double)u * (double)Y, sm);
  if (threadIdx.x == 0) {
    double* s = slot + blockIdx.x * 4;
    s[0] = su;
    s[1] = qu;
    s[2] = mx;
    s[3] = my;
    if (blockIdx.x == 0) *fctr = 0u;
  }
}

template <bool AB, bool FAST>
__device__ inline void tile_loop(const float4* sxy4, const float2* su2,
                                 const float2* sb2, const float x[4],
                                 const float y[4], const float al[4],
                                 float rr0, float rr1, float acc[4][3],
                                 float& sdo, float& sqo) {
  float sd = 0.f, sq = 0.f;
#pragma unroll 2
  for (int jj = 0; jj < JT / 2; ++jj) {
    float4 xy = sxy4[jj];  // {x0,y0,x1,y1} two j points (LDS broadcast)
    float2 u2 = su2[jj];
    float bj[2];
    if constexpr (AB) {
      float2 b2v = sb2[jj];
      bj[0] = b2v.x;
      bj[1] = b2v.y;
    }
    float xj[2] = {xy.x, xy.z};
    float yj[2] = {xy.y, xy.w};
    float uj[2] = {u2.x, u2.y};
#pragma unroll
    for (int q = 0; q < 2; ++q) {
#pragma unroll
      for (int i = 0; i < 4; ++i) {
        float dx = x[i] - xj[q];
        float dy = y[i] - yj[q];
        float s = fmaf(dy, dy, dx * dx);  // d2_centered * (ln2e/2s2^2)
        float k2 = EXP2F(-s);
        float k0, k1;
        if constexpr (FAST) {
          float t = k2 * k2;
          k1 = t * t;  // k2^4  (sigma ratio 1:2)
          float t1 = k1 * k1;
          k0 = t1 * t1;  // k2^16 (sigma ratio 1:4)
        } else {
          k1 = EXP2F(-s * rr1);
          k0 = EXP2F(-s * rr0);
        }
        acc[i][0] = fmaf(uj[q], k0, acc[i][0]);
        acc[i][1] = fmaf(uj[q], k1, acc[i][1]);
        acc[i][2] = fmaf(uj[q], k2, acc[i][2]);
        if constexpr (AB) {
          float d2u = fmaxf((s + al[i]) - bj[q], 0.f);
          sd += SQRTF(d2u);
          sq += d2u;
        }
      }
    }
  }
  sdo = sd;
  sqo = sq;
}

__global__ __launch_bounds__(256) void pair_kernel(
    const float2* __restrict__ pxy, const float* __restrict__ pu,
    const double* __restrict__ slot, double* __restrict__ paa,
    double* __restrict__ pbb, double* __restrict__ pab,
    double* __restrict__ psd, double* __restrict__ psq,
    unsigned* __restrict__ fctr, const float* __restrict__ log_sigmas,
    const float* __restrict__ g_w1, const float* __restrict__ g_b1,
    const float* __restrict__ g_w2, const float* __restrict__ g_b2,
    const float* __restrict__ bias, float* __restrict__ out, int n) {
  __shared__ __align__(16) float2 sxy[JT];
  __shared__ __align__(16) float su[JT];
  __shared__ __align__(16) float sb[JT];
  __shared__ double sm[4];
  __shared__ double smean[8];
  __shared__ int lastf;

  int b = blockIdx.x;
  int m, it, jt = 0, j0, pidx;
  if (b < NJOB_AB) {  // AB first (heavier), light tri jobs drain last
    m = 2;
    pidx = b;
    it = b >> 7;            // 8 i-tiles
    j0 = (b & 127) * JT;    // 128 j-chunks
  } else {
    int r = b - NJOB_AB;
    m = (r < NJOB_TRI) ? 0 : 1;
    if (m == 1) r -= NJOB_TRI;
    pidx = r;
    int tile = r >> 4;
    int q = r & 15;
    int idx = tile, len = T8;
    it = 0;
    while (idx >= len) {
      idx -= len;
      --len;
      ++it;
    }
    jt = it + idx;
    j0 = jt * ITILE + q * JT;
  }
  const float2* pxyI = pxy + ((m == 1) ? n : 0);
  const float* puI = pu + ((m == 1) ? n : 0);
  const float2* pxyJ = pxy + ((m == 0) ? 0 : n);
  const float* puJ = pu + ((m == 0) ? 0 : n);

  float cx = 0.f, cy = 0.f, cx2 = 0.f, cy2 = 0.f, cc = 0.f;
  if (m == 2) {
    slot_reduce(slot, smean);  // wave 0; consumed after the barrier below
  }

  float s0 = __expf(log_sigmas[0]);
  float s1 = __expf(log_sigmas[1]);
  float s2 = __expf(log_sigmas[2]);
  float rr0 = (s2 * s2) / (s0 * s0);
  float rr1 = (s2 * s2) / (s1 * s1);
  bool fast = (fabsf(rr0 - 16.f) <= 0.016f) && (fabsf(rr1 - 4.f) <= 0.004f);

  if (m == 2) {
    __syncthreads();
    cx = (float)(smean[2] / smean[0] - smean[6] / smean[4]);
    cy = (float)(smean[3] / smean[0] - smean[7] / smean[4]);
    cx2 = 2.f * cx;
    cy2 = 2.f * cy;
    cc = cx * cx + cy * cy;
  }

  if (threadIdx.x < JT) {
    float2 v = pxyJ[j0 + threadIdx.x];
    sxy[threadIdx.x] = v;
    su[threadIdx.x] = puJ[j0 + threadIdx.x];
    if (m == 2) sb[threadIdx.x] = fmaf(cx2, v.x, cy2 * v.y);  // beta_j
  }
  __syncthreads();

  int i0 = it * ITILE + threadIdx.x;
  float x[4], y[4], u[4], al[4];
#pragma unroll
  for (int i = 0; i < 4; ++i) {
    float2 P = pxyI[i0 + i * 256];
    u[i] = puI[i0 + i * 256];
    x[i] = P.x;
    y[i] = P.y;
    al[i] = 0.f;
    if (m == 2) {  // center i-side; alpha recovers uncentered distance
      x[i] -= cx;
      y[i] -= cy;
      al[i] = fmaf(cx2, x[i], cy2 * y[i]) + cc;
    }
  }

  float accf[4][3] = {};
  float sd = 0.f, sq = 0.f;
  const float4* sxy4 = reinterpret_cast<const float4*>(sxy);
  const float2* su2 = reinterpret_cast<const float2*>(su);
  const float2* sb2 = reinterpret_cast<const float2*>(sb);
  if (m == 2) {
    if (fast)
      tile_loop<true, true>(sxy4, su2, sb2, x, y, al, rr0, rr1, accf, sd, sq);
    else
      tile_loop<true, false>(sxy4, su2, sb2, x, y, al, rr0, rr1, accf, sd, sq);
  } else {
    if (fast)
      tile_loop<false, true>(sxy4, su2, sb2, x, y, al, rr0, rr1, accf, sd, sq);
    else
      tile_loop<false, false>(sxy4, su2, sb2, x, y, al, rr0, rr1, accf, sd,
                              sq);
  }

  double wgt = (m != 2 && jt != it) ? 2.0 : 1.0;  // symmetric off-diag tiles
  double c0 = 0.0, c1 = 0.0, c2 = 0.0;
#pragma unroll
  for (int i = 0; i < 4; ++i) {
    c0 += (double)u[i] * accf[i][0];
    c1 += (double)u[i] * accf[i][1];
    c2 += (double)u[i] * accf[i][2];
  }
  double r0 = bred(c0, sm) * wgt;
  double r1 = bred(c1, sm) * wgt;
  double r2d = bred(c2, sm) * wgt;
  double* prow = (m == 0) ? paa : (m == 1) ? pbb : pab;
  int stride = (m == 2) ? NJOB_AB : NJOB_TRI;
  if (threadIdx.x == 0) {
    prow[0 * stride + pidx] = r0;
    prow[1 * stride + pidx] = r1;
    prow[2 * stride + pidx] = r2d;
  }
  if (m == 2) {
    double rsd = bred((double)sd, sm);
    double rsq = bred((double)sq, sm);
    if (threadIdx.x == 0) {
      psd[pidx] = rsd;
      psq[pidx] = rsq;
    }
  }

  // ---- last-block final reduction (ticket + device fence) ----
  if (threadIdx.x == 0) {
    __threadfence();
    unsigned old = atomicAdd(fctr, 1u);
    lastf = (old == NBLK - 1) ? 1 : 0;
  }
  __syncthreads();
  if (!lastf) return;
  __threadfence();

  slot_reduce(slot, smean);
  __syncthreads();
  int t = threadIdx.x;
  double vaa[3], vbb[3], vab[3];
  for (int s = 0; s < 3; ++s) {
    const double* pa = paa + s * NJOB_TRI;
    const double* pb = pbb + s * NJOB_TRI;
    const double* pc = pab + s * NJOB_AB;
    double va = pa[t] + pa[t + 256] + ((t < 64) ? pa[t + 512] : 0.0);
    double vb = pb[t] + pb[t + 256] + ((t < 64) ? pb[t + 512] : 0.0);
    double vc = pc[t] + pc[t + 256] + pc[t + 512] + pc[t + 768];
    vaa[s] = bred(va, sm);
    vbb[s] = bred(vb, sm);
    vab[s] = bred(vc, sm);
  }
  double sdt = bred(psd[t] + psd[t + 256] + psd[t + 512] + psd[t + 768], sm);
  double sqt = bred(psq[t] + psq[t + 256] + psq[t + 512] + psq[t + 768], sm);

  if (threadIdx.x == 0) {
    double Sb = smean[0], Qb = smean[1], St = smean[4], Qt = smean[5];
    double pband[3];
    for (int s = 0; s < 3; ++s)
      pband[s] = vaa[s] / (Sb * Sb) + vbb[s] / (St * St) -
                 2.0 * vab[s] / (Sb * St);
    double s2d = (double)s2;
    double r2sq = (double)L2E / (2.0 * s2d * s2d);
    double sd_real = sdt / sqrt(r2sq);
    double sq_real = sqt / r2sq;
    double NN = (double)n;
    double NM = NN * NN;
    double mean_d = sd_real / NM;
    double var_d = (sq_real - sd_real * sd_real / NM) / (NM - 1.0);
    double wv = (Qb / (Sb * Sb) - 1.0 / NN) / (NN - 1.0) +
                (Qt / (St * St) - 1.0 / NN) / (NN - 1.0);
    float st[4] = {(float)mean_d, (float)var_d, 0.f, (float)wv};
    float gl[3] = {g_b2[0], g_b2[1], g_b2[2]};
    for (int k = 0; k < 32; ++k) {
      float h = g_b1[k];
      for (int c = 0; c < 4; ++c) h = fmaf(st[c], g_w1[c * 32 + k], h);
      h = fmaxf(h, 0.f);
      for (int s = 0; s < 3; ++s) gl[s] = fmaf(h, g_w2[k * 3 + s], gl[s]);
    }
    float gw[3];
    float gsum = 0.f;
    for (int s = 0; s < 3; ++s) {
      gw[s] = fmaxf(gl[s], 0.f) + log1pf(__expf(-fabsf(gl[s])));
      gsum += gw[s];
    }
    double r = 0.0;
    for (int s = 0; s < 3; ++s) r += (double)(gw[s] / gsum) * pband[s];
    out[0] = (float)(r + (double)bias[0]);
  }
}

extern "C" void kernel_launch(void* const* d_in, const int* in_sizes, int n_in,
                              void* d_out, int out_size, void* d_ws,
                              size_t ws_size, hipStream_t stream) {
  const float* base = (const float*)d_in[0];
  const float* target = (const float*)d_in[1];
  const float* log_sigmas = (const float*)d_in[2];
  const float* log_scale = (const float*)d_in[3];
  const float* wn_w1 = (const float*)d_in[4];
  const float* wn_b1 = (const float*)d_in[5];
  const float* wn_w2 = (const float*)d_in[6];
  const float* wn_b2 = (const float*)d_in[7];
  const float* g_w1 = (const float*)d_in[8];
  const float* g_b1 = (const float*)d_in[9];
  const float* g_w2 = (const float*)d_in[10];
  const float* g_b2 = (const float*)d_in[11];
  const float* bias = (const float*)d_in[12];
  int n = in_sizes[0] / 2;  // 8192

  double* dbase = (double*)d_ws;
  double* slot = dbase;                // 64 * 4 = 256
  double* paa = dbase + 256;           // 3 * 576
  double* pbb = paa + 3 * NJOB_TRI;    // 3 * 576
  double* pab = pbb + 3 * NJOB_TRI;    // 3 * 1024
  double* psd = pab + 3 * NJOB_AB;     // 1024
  double* psq = psd + NJOB_AB;         // 1024
  double* dend = psq + NJOB_AB;
  float2* pxy = (float2*)dend;         // 2n
  float* pu = (float*)(pxy + 2 * n);   // 2n
  unsigned* fctr = (unsigned*)(pu + 2 * n);

  prep_kernel<<<(2 * n) / 256, 256, 0, stream>>>(
      base, target, log_sigmas, log_scale, wn_w1, wn_b1, wn_w2, wn_b2, pxy, pu,
      slot, fctr, n);
  pair_kernel<<<NBLK, 256, 0, stream>>>(pxy, pu, slot, paa, pbb, pab, psd, psq,
                                        fctr, log_sigmas, g_w1, g_b1, g_w2,
                                        g_b2, bias, (float*)d_out, n);
}